// Round 18
// baseline (181.772 us; speedup 1.0000x reference)
//
#include <hip/hip_runtime.h>

#define NB 8192
#define NT 365
#define NF 5
#define NH 10
#define NG 40   // 4*NH
#define GPW 6   // 10-lane groups per wave (lanes 60..63 dead)

// One lane owns ONE hidden unit u (its 4 gate columns f,i,o,g; c[u]; h[u]).
// Cross-lane traffic: 10 ds_bpermute per step to broadcast the group's h.
// g-gate weights/bias pre-scaled x2 (tanh(x) = 2*sigmoid(2x)-1).
// x prefetched in 8-step chunks of 10 float4 into a register double buffer.
//
// NEW vs r16:
//  * amdgpu_waves_per_eu(1,2): r7-r16 showed VGPR_Count pinned at 56-96 --
//    the allocator targets ~5 waves/SIMD (~102 VGPR budget) no matter what
//    __launch_bounds__ says, and sheds the 68 loop-invariant weights
//    (remat-from-global), putting ~200cyc of VMEM latency on the serial
//    chain every step. max=2 waves/EU raises the budget to 256 VGPRs.
//  * Gate dots use TWO partial accumulators each (8-deep chains instead of
//    15-deep): chain -40cyc, 8 independent FMA streams for the scheduler.
// Time model: kernel is serial-chain-bound (wall = 365 x chain; occupancy-
// invariant, r8/r13/r14 evidence), so only chain cuts matter.
__global__ __launch_bounds__(256, 1) __attribute__((amdgpu_waves_per_eu(1, 2)))
void lstm_unit_wb(const float* __restrict__ x,
                  const float* __restrict__ w_ih,
                  const float* __restrict__ w_hh,
                  const float* __restrict__ bias,
                  const float* __restrict__ fc_w,
                  const float* __restrict__ fc_b,
                  float* __restrict__ out)
{
    const int lane = threadIdx.x & 63;
    const int wid  = (blockIdx.x * 256 + threadIdx.x) >> 6;  // global wave id
    const int g    = lane / NH;          // group in wave (0..5; 6 => dead)
    const int u    = lane % NH;          // owned hidden unit
    const long b0  = (long)wid * GPW + g;
    const bool alive = (g < GPW) && (b0 < NB);
    const long b   = alive ? b0 : 0;     // clamped for safe addressing

    float* h_out = out + NB;
    float* c_out = h_out + (size_t)NB * NT * NH;

    // ---- per-lane weights: 4 columns x (5 ih + 10 hh) + 4 bias ----
    float wih[NF][4], whh[NH][4], bq[4];
    #pragma unroll
    for (int q = 0; q < 4; ++q) {
        const float gs = (q == 3) ? 2.0f : 1.0f;
        const int col = q * NH + u;
        #pragma unroll
        for (int f = 0; f < NF; ++f) wih[f][q] = w_ih[f * NG + col] * gs;
        #pragma unroll
        for (int j = 0; j < NH; ++j) whh[j][q] = w_hh[j * NG + col] * gs;
        bq[q] = bias[col] * gs;
    }

    // bpermute byte-addresses of the 10 group members
    int aj[NH];
    #pragma unroll
    for (int j = 0; j < NH; ++j) aj[j] = (g * NH + j) * 4;

    float hAll[NH];
    #pragma unroll
    for (int j = 0; j < NH; ++j) hAll[j] = 0.f;
    float c = 0.f;

    const float* xp = x + (size_t)b * NT * NF;
    float* hcp = h_out + (size_t)b * NT * NH + u;
    float* ccp = c_out + (size_t)b * NT * NH + u;

    float A[40], B[40];   // x double-buffer: 8 steps x 5 features each

// load one 8-step chunk (40 contiguous floats, 10 float4)
#define LD8(dst, t0) { \
    const float4* p4 = reinterpret_cast<const float4*>(xp + (size_t)(t0) * NF); \
    _Pragma("unroll") \
    for (int i = 0; i < 10; ++i) { \
        float4 v = p4[i]; \
        dst[i*4+0] = v.x; dst[i*4+1] = v.y; dst[i*4+2] = v.z; dst[i*4+3] = v.w; } }

// tail: 5 steps = 25 floats (6 float4 + 1 dword), exactly to end of row
#define LDT(dst) { \
    const float4* p4 = reinterpret_cast<const float4*>(xp + (size_t)360 * NF); \
    _Pragma("unroll") \
    for (int i = 0; i < 6; ++i) { \
        float4 v = p4[i]; \
        dst[i*4+0] = v.x; dst[i*4+1] = v.y; dst[i*4+2] = v.z; dst[i*4+3] = v.w; } \
    dst[24] = xp[360 * NF + 24]; }

// one LSTM step; s is a literal. Each gate dot runs as TWO partial chains
// (a: bias + x0,x1 + h0..h4 = 8 deps; b: x2,x3,x4 + h5..h9 = 8 deps).
#define STEP(buf, s) { \
    float r0a = bq[0], r1a = bq[1], r2a = bq[2], r3a = bq[3]; \
    float r0b = 0.f,  r1b = 0.f,  r2b = 0.f,  r3b = 0.f; \
    _Pragma("unroll") \
    for (int f = 0; f < 2; ++f) { \
        const float xv = buf[(s) * NF + f]; \
        r0a = fmaf(xv, wih[f][0], r0a); r1a = fmaf(xv, wih[f][1], r1a); \
        r2a = fmaf(xv, wih[f][2], r2a); r3a = fmaf(xv, wih[f][3], r3a); } \
    _Pragma("unroll") \
    for (int f = 2; f < NF; ++f) { \
        const float xv = buf[(s) * NF + f]; \
        r0b = fmaf(xv, wih[f][0], r0b); r1b = fmaf(xv, wih[f][1], r1b); \
        r2b = fmaf(xv, wih[f][2], r2b); r3b = fmaf(xv, wih[f][3], r3b); } \
    _Pragma("unroll") \
    for (int j = 0; j < 5; ++j) { \
        const float hv = hAll[j]; \
        r0a = fmaf(hv, whh[j][0], r0a); r1a = fmaf(hv, whh[j][1], r1a); \
        r2a = fmaf(hv, whh[j][2], r2a); r3a = fmaf(hv, whh[j][3], r3a); } \
    _Pragma("unroll") \
    for (int j = 5; j < NH; ++j) { \
        const float hv = hAll[j]; \
        r0b = fmaf(hv, whh[j][0], r0b); r1b = fmaf(hv, whh[j][1], r1b); \
        r2b = fmaf(hv, whh[j][2], r2b); r3b = fmaf(hv, whh[j][3], r3b); } \
    const float r0 = r0a + r0b, r1 = r1a + r1b; \
    const float r2 = r2a + r2b, r3 = r3a + r3b; \
    const float sf = __builtin_amdgcn_rcpf(1.0f + __expf(-r0)); \
    const float si = __builtin_amdgcn_rcpf(1.0f + __expf(-r1)); \
    const float so = __builtin_amdgcn_rcpf(1.0f + __expf(-r2)); \
    const float tg = fmaf(2.0f, __builtin_amdgcn_rcpf(1.0f + __expf(-r3)), -1.0f); \
    c = fmaf(sf, c, si * tg); \
    const float th = fmaf(2.0f, __builtin_amdgcn_rcpf(1.0f + __expf(-2.0f * c)), -1.0f); \
    const float h = so * th; \
    _Pragma("unroll") \
    for (int j = 0; j < NH; ++j) \
        hAll[j] = __int_as_float(__builtin_amdgcn_ds_bpermute(aj[j], __float_as_int(h))); \
    if (alive) { hcp[(s) * NH] = h; ccp[(s) * NH] = c; } }

#define RUN8(buf) { STEP(buf,0) STEP(buf,1) STEP(buf,2) STEP(buf,3) \
                    STEP(buf,4) STEP(buf,5) STEP(buf,6) STEP(buf,7) \
                    hcp += 8 * NH; ccp += 8 * NH; }

    LD8(A, 0)
    // 44 full chunks in 22 statically ping-ponged pairs: t = 0..351
    for (int cc = 0; cc < 22; ++cc) {
        const int t0 = cc * 16;
        LD8(B, t0 + 8)      // prefetch next chunk, then run current
        RUN8(A)
        LD8(A, t0 + 16)     // cc=21 -> t=352..359, in-bounds
        RUN8(B)
    }
    // A holds chunk t=352..359; prefetch tail, run, then 5 tail steps
    LDT(B)
    RUN8(A)
    { STEP(B,0) STEP(B,1) STEP(B,2) STEP(B,3) STEP(B,4) }   // t=360..364

    // ---- fc head: lane u==0 of each live group has hAll = h_{T-1} ----
    if (alive && u == 0) {
        float acc = fc_b[0];
        #pragma unroll
        for (int j = 0; j < NH; ++j) acc = fmaf(hAll[j], fc_w[j], acc);
        out[b] = acc;
    }
}

extern "C" void kernel_launch(void* const* d_in, const int* in_sizes, int n_in,
                              void* d_out, int out_size, void* d_ws, size_t ws_size,
                              hipStream_t stream) {
    const float* x    = (const float*)d_in[0];
    const float* wih  = (const float*)d_in[1];
    const float* whh  = (const float*)d_in[2];
    const float* bias = (const float*)d_in[3];
    const float* fcw  = (const float*)d_in[4];
    const float* fcb  = (const float*)d_in[5];
    float* out = (float*)d_out;

    const int nwave  = (NB + GPW - 1) / GPW;          // 1366 waves of work
    const int blocks = (nwave * 64 + 255) / 256;      // 342 blocks
    lstm_unit_wb<<<blocks, 256, 0, stream>>>(x, wih, whh, bias, fcw, fcb, out);
}

// Round 20
// 179.377 us; speedup vs baseline: 1.0133x; 1.0133x over previous
//
#include <hip/hip_runtime.h>

#define NB 8192
#define NT 365
#define NF 5
#define NH 10
#define NG 40   // 4*NH
#define GPW 6   // 10-lane groups per wave (lanes 60..63 dead)

// One lane owns ONE hidden unit u (4 gate cols f,i,o,g; c[u]; h[u]).
// 10 ds_bpermute per step broadcast the group's h. g-gate weights/bias
// pre-scaled x2 (tanh(x) = 2*sigmoid(2x)-1). Dual-accumulator dots (r18).
//
// NEW vs r18: x streams through a per-wave LDS double-buffer instead of an
// 80-register A/B file. Theory (r7-r18 counters): the allocator never keeps
// the 64 weights in VGPRs because total demand (~170) exceeds its ~92-128
// budget -- it spills the weights to scratch and re-loads 256B/lane/step,
// saturating the per-CU L1/scratch path (~1200cyc/step = the invariant
// wall). Removing the 80-reg x-buffer drops demand to ~114 so the weights
// can finally be register-resident; x costs only 20B/lane/step from LDS
// (10-lane broadcast reads, conflict-free).
// Staging: lane (g,u) loads float4 quarter u of element g's 40-float chunk
// (1 global_load_dwordx4 + 1 ds_write_b128 per lane per 8 steps).
__global__ __launch_bounds__(256, 1)
void lstm_xl(const float* __restrict__ x,
             const float* __restrict__ w_ih,
             const float* __restrict__ w_hh,
             const float* __restrict__ bias,
             const float* __restrict__ fc_w,
             const float* __restrict__ fc_b,
             float* __restrict__ out)
{
    __shared__ float xlds[4 * 480];   // [wave][2 bufs][6 elem][40 floats]

    const int tid  = threadIdx.x;
    const int lane = tid & 63;
    const int wv   = tid >> 6;                       // wave in block
    const int wid  = (blockIdx.x * 256 + tid) >> 6;  // global wave id
    const int g    = lane / NH;          // group (0..5; 6 => dead lane)
    const int u    = lane % NH;          // owned hidden unit / stage quarter
    const long b0  = (long)wid * GPW + g;
    const bool alive = (g < GPW) && (b0 < NB);
    const long b   = alive ? b0 : 0;     // clamped for safe addressing

    float* h_out = out + NB;
    float* c_out = h_out + (size_t)NB * NT * NH;

    // ---- per-lane weights: 4 cols x (5 ih + 10 hh) + 4 bias ----
    float wih[NF][4], whh[NH][4], bq[4];
    #pragma unroll
    for (int q = 0; q < 4; ++q) {
        const float gs = (q == 3) ? 2.0f : 1.0f;
        const int col = q * NH + u;
        #pragma unroll
        for (int f = 0; f < NF; ++f) wih[f][q] = w_ih[f * NG + col] * gs;
        #pragma unroll
        for (int j = 0; j < NH; ++j) whh[j][q] = w_hh[j * NG + col] * gs;
        bq[q] = bias[col] * gs;
    }

    // bpermute byte-addresses of the 10 group members
    int aj[NH];
    #pragma unroll
    for (int j = 0; j < NH; ++j) aj[j] = (g * NH + j) * 4;

    float hAll[NH];
    #pragma unroll
    for (int j = 0; j < NH; ++j) hAll[j] = 0.f;
    float c = 0.f;

    const float* xp = x + (size_t)b * NT * NF;   // b*29200B: 16B-aligned
    float* hcp = h_out + (size_t)b * NT * NH + u;
    float* ccp = c_out + (size_t)b * NT * NH + u;

    float* wb0 = &xlds[wv * 480];        // this wave's buffer 0
    float* wb1 = wb0 + 240;              // buffer 1
    const float* xg0 = wb0 + g * 40;     // this lane's read base, buf 0
    const float* xg1 = wb1 + g * 40;     // buf 1

    float4 G;            // staged chunk quarter (4 VGPRs, reused)
    float  Gx = 0.f;     // tail 25th float

// issue this lane's global quarter-load of chunk at t0 (t0 multiple of 8:
// byte offset t0*20 + u*16 is 16B-aligned)
#define GLOAD(t0) { G = *reinterpret_cast<const float4*>(xp + (size_t)(t0) * NF + u * 4); }
// commit staged quarter to an LDS buffer
#define WRITE(wb) { if (g < GPW) *reinterpret_cast<float4*>((wb) + g * 40 + u * 4) = G; }
// tail chunk: 25 floats = 6 float4 (u<6) + 1 dword (u==6)
#define GLOADT { if (u < 6) G = *reinterpret_cast<const float4*>(xp + 1800 + u * 4); \
                 else if (u == 6) Gx = xp[1824]; }
#define WRITET(wb) { if (g < GPW) { \
    if (u < 6) *reinterpret_cast<float4*>((wb) + g * 40 + u * 4) = G; \
    else if (u == 6) (wb)[g * 40 + 24] = Gx; } }

// one LSTM step; XB = lane's LDS read base, s literal. x reads are 5
// ds_read_b32 broadcast across the 10-lane group. Dual-accumulator dots.
#define STEP(XB, s) { \
    const float xv0 = (XB)[(s)*5+0], xv1 = (XB)[(s)*5+1], xv2 = (XB)[(s)*5+2]; \
    const float xv3 = (XB)[(s)*5+3], xv4 = (XB)[(s)*5+4]; \
    float r0a = bq[0], r1a = bq[1], r2a = bq[2], r3a = bq[3]; \
    float r0b = 0.f,  r1b = 0.f,  r2b = 0.f,  r3b = 0.f; \
    r0a = fmaf(xv0, wih[0][0], r0a); r1a = fmaf(xv0, wih[0][1], r1a); \
    r2a = fmaf(xv0, wih[0][2], r2a); r3a = fmaf(xv0, wih[0][3], r3a); \
    r0a = fmaf(xv1, wih[1][0], r0a); r1a = fmaf(xv1, wih[1][1], r1a); \
    r2a = fmaf(xv1, wih[1][2], r2a); r3a = fmaf(xv1, wih[1][3], r3a); \
    r0b = fmaf(xv2, wih[2][0], r0b); r1b = fmaf(xv2, wih[2][1], r1b); \
    r2b = fmaf(xv2, wih[2][2], r2b); r3b = fmaf(xv2, wih[2][3], r3b); \
    r0b = fmaf(xv3, wih[3][0], r0b); r1b = fmaf(xv3, wih[3][1], r1b); \
    r2b = fmaf(xv3, wih[3][2], r2b); r3b = fmaf(xv3, wih[3][3], r3b); \
    r0b = fmaf(xv4, wih[4][0], r0b); r1b = fmaf(xv4, wih[4][1], r1b); \
    r2b = fmaf(xv4, wih[4][2], r2b); r3b = fmaf(xv4, wih[4][3], r3b); \
    _Pragma("unroll") \
    for (int j = 0; j < 5; ++j) { \
        const float hv = hAll[j]; \
        r0a = fmaf(hv, whh[j][0], r0a); r1a = fmaf(hv, whh[j][1], r1a); \
        r2a = fmaf(hv, whh[j][2], r2a); r3a = fmaf(hv, whh[j][3], r3a); } \
    _Pragma("unroll") \
    for (int j = 5; j < NH; ++j) { \
        const float hv = hAll[j]; \
        r0b = fmaf(hv, whh[j][0], r0b); r1b = fmaf(hv, whh[j][1], r1b); \
        r2b = fmaf(hv, whh[j][2], r2b); r3b = fmaf(hv, whh[j][3], r3b); } \
    const float r0 = r0a + r0b, r1 = r1a + r1b; \
    const float r2 = r2a + r2b, r3 = r3a + r3b; \
    const float sf = __builtin_amdgcn_rcpf(1.0f + __expf(-r0)); \
    const float si = __builtin_amdgcn_rcpf(1.0f + __expf(-r1)); \
    const float so = __builtin_amdgcn_rcpf(1.0f + __expf(-r2)); \
    const float tg = fmaf(2.0f, __builtin_amdgcn_rcpf(1.0f + __expf(-r3)), -1.0f); \
    c = fmaf(sf, c, si * tg); \
    const float th = fmaf(2.0f, __builtin_amdgcn_rcpf(1.0f + __expf(-2.0f * c)), -1.0f); \
    const float h = so * th; \
    _Pragma("unroll") \
    for (int j = 0; j < NH; ++j) \
        hAll[j] = __int_as_float(__builtin_amdgcn_ds_bpermute(aj[j], __float_as_int(h))); \
    if (alive) { hcp[(s) * NH] = h; ccp[(s) * NH] = c; } }

#define RUN8(XB) { STEP(XB,0) STEP(XB,1) STEP(XB,2) STEP(XB,3) \
                   STEP(XB,4) STEP(XB,5) STEP(XB,6) STEP(XB,7) \
                   hcp += 8 * NH; ccp += 8 * NH; }

    // prologue: chunk 0 into buf0
    GLOAD(0) WRITE(wb0)
    // 44 full chunks in 22 statically ping-ponged pairs (t = 0..351)
    for (int cc = 0; cc < 22; ++cc) {
        GLOAD(16 * cc + 8)          // chunk 2cc+1 (issued before 8 steps)
        RUN8(xg0)                   // chunk 2cc
        WRITE(wb1)
        GLOAD(16 * cc + 16)         // chunk 2cc+2 (cc=21 -> t0=352, in-bounds)
        RUN8(xg1)                   // chunk 2cc+1
        WRITE(wb0)
    }
    // buf0 = chunk 44 (t=352..359); stage tail, run, then 5 tail steps
    GLOADT
    RUN8(xg0)
    WRITET(wb1)
    { STEP(xg1,0) STEP(xg1,1) STEP(xg1,2) STEP(xg1,3) STEP(xg1,4) }  // t=360..364

    // ---- fc head: lane u==0 of each live group has hAll = h_{T-1} ----
    if (alive && u == 0) {
        float acc = fc_b[0];
        #pragma unroll
        for (int j = 0; j < NH; ++j) acc = fmaf(hAll[j], fc_w[j], acc);
        out[b] = acc;
    }
}

extern "C" void kernel_launch(void* const* d_in, const int* in_sizes, int n_in,
                              void* d_out, int out_size, void* d_ws, size_t ws_size,
                              hipStream_t stream) {
    const float* x    = (const float*)d_in[0];
    const float* wih  = (const float*)d_in[1];
    const float* whh  = (const float*)d_in[2];
    const float* bias = (const float*)d_in[3];
    const float* fcw  = (const float*)d_in[4];
    const float* fcb  = (const float*)d_in[5];
    float* out = (float*)d_out;

    const int nwave  = (NB + GPW - 1) / GPW;          // 1366 waves of work
    const int blocks = (nwave * 64 + 255) / 256;      // 342 blocks
    lstm_xl<<<blocks, 256, 0, stream>>>(x, wih, whh, bias, fcw, fcb, out);
}